// Round 5
// baseline (254.815 us; speedup 1.0000x reference)
//
#include <hip/hip_runtime.h>
#include <hip/hip_bf16.h>

typedef unsigned short u16;
typedef __attribute__((ext_vector_type(8))) short bf16x8;
typedef __attribute__((ext_vector_type(4))) float f32x4;

#define QSCALE 0.180336880f   // 0.125 * log2(e): softmax computed in exp2 domain

#define DEV static __device__ __forceinline__

DEV u16 f2bf(float f) {
  union { float f; unsigned u; } v; v.f = f;
  unsigned r = v.u + 0x7fffu + ((v.u >> 16) & 1u);  // round-to-nearest-even
  return (u16)(r >> 16);
}

DEV unsigned pk2(float a, float b) {   // two f32 -> packed bf16x2 (RNE)
  union { __hip_bfloat162 h; unsigned u; } c;
  c.h = __float22bfloat162_rn(make_float2(a, b));
  return c.u;
}

DEV void gll16(void* lds, const void* g) {
  __builtin_amdgcn_global_load_lds(
      (const __attribute__((address_space(1))) unsigned int*)g,
      (__attribute__((address_space(3))) unsigned int*)lds, 16, 0, 0);
}

// ---------------- pack: fp32 -> bf16 ----------------
__global__ __launch_bounds__(256) void cvt_f32_to_bf16(const float* __restrict__ in,
                                                       u16* __restrict__ out, int n4) {
  int i = blockIdx.x * blockDim.x + threadIdx.x;
  int stride = gridDim.x * blockDim.x;
  for (; i < n4; i += stride) {
    float4 f = ((const float4*)in)[i];
    ushort4 u;
    u.x = f2bf(f.x); u.y = f2bf(f.y); u.z = f2bf(f.z); u.w = f2bf(f.w);
    ((ushort4*)out)[i] = u;
  }
}

// ---------------- pack: W[K][N] fp32 -> Wt[N][K] bf16, cols < sn scaled ----------------
__global__ __launch_bounds__(256) void transpose_cvt(const float* __restrict__ W,
                                                     u16* __restrict__ Wt,
                                                     int K, int N, int sn, float sval) {
  __shared__ u16 t[64][65];
  const int k0 = blockIdx.x * 64, n0 = blockIdx.y * 64;
  const int tid = threadIdx.x;
  const int rr = tid >> 4;        // 0..15
  const int cc = (tid & 15) * 4;  // 0..60
  const float scl = (n0 < sn) ? sval : 1.0f;   // n0 is 64-aligned, sn is 1024
#pragma unroll
  for (int i = 0; i < 4; ++i) {
    const int row = rr * 4 + i;
    float4 f = *(const float4*)&W[(size_t)(k0 + row) * N + n0 + cc];
    t[row][cc + 0] = f2bf(f.x * scl);
    t[row][cc + 1] = f2bf(f.y * scl);
    t[row][cc + 2] = f2bf(f.z * scl);
    t[row][cc + 3] = f2bf(f.w * scl);
  }
  __syncthreads();
#pragma unroll
  for (int i = 0; i < 4; ++i) {
    const int n = rr * 4 + i;
    ushort4 u;
    u.x = t[cc + 0][n]; u.y = t[cc + 1][n]; u.z = t[cc + 2][n]; u.w = t[cc + 3][n];
    *(ushort4*)&Wt[(size_t)(n0 + n) * K + k0 + cc] = u;
  }
}

// ---------------- transpose V part of qkv: -> vT[bh][d][t] (fallback path) --------
__global__ __launch_bounds__(256) void transpose_v(const u16* __restrict__ qkv,
                                                   u16* __restrict__ vT) {
  __shared__ u16 t[64][72];
  const int bh = blockIdx.y;          // b*16+h
  const int b = bh >> 4, h = bh & 15;
  const int t0 = blockIdx.x * 64;
  const int tid = threadIdx.x;
  const int row = tid >> 2;           // token within tile, 0..63
  const int cg = (tid & 3) * 16;      // d group
  const size_t src = (size_t)b * 2048 * 3072 + (size_t)(t0 + row) * 3072 + 2048 + h * 64 + cg;
  bf16x8 v0 = *(const bf16x8*)&qkv[src];
  bf16x8 v1 = *(const bf16x8*)&qkv[src + 8];
#pragma unroll
  for (int i = 0; i < 8; ++i) { t[row][cg + i] = (u16)v0[i]; t[row][cg + 8 + i] = (u16)v1[i]; }
  __syncthreads();
  const int d = tid >> 2;             // 0..63
  const int tg = (tid & 3) * 16;
  bf16x8 o0, o1;
#pragma unroll
  for (int i = 0; i < 8; ++i) { o0[i] = (short)t[tg + i][d]; o1[i] = (short)t[tg + 8 + i][d]; }
  u16* dst = &vT[((size_t)bh * 64 + d) * 2048 + t0 + tg];
  *(bf16x8*)dst = o0;
  *(bf16x8*)(dst + 8) = o1;
}

// ---------------- bf16 GEMM: C[M][N] = A[M][K] * Bt[N][K]^T + bias ----------------
// 128x128 tile, BK=64, 256 threads (4 waves, 2x2), each wave 64x64 = 4x4 frags.
// Bias for cols < qn scaled by QSCALE. If vTout != null, cols >= vn0 are written
// transposed to vT[bh][d][t] layout instead of Cout (fused V-transpose).
template<bool OUT_BF16>
__global__ __launch_bounds__(256) void gemm_bf16(const u16* __restrict__ A,
                                                 const u16* __restrict__ Bt,
                                                 const float* __restrict__ bias,
                                                 void* __restrict__ Cout,
                                                 int M, int N, int K, int qn,
                                                 u16* __restrict__ vTout, int vn0) {
  __shared__ __align__(16) u16 As[128][64];
  __shared__ __align__(16) u16 Bs[128][64];
  const int tid = threadIdx.x;
  const int wave = tid >> 6, lane = tid & 63;
  const int g = lane >> 4, lr = lane & 15;
  const int bm = blockIdx.x * 128, bn = blockIdx.y * 128;
  const int wm = (wave >> 1) * 64, wn = (wave & 1) * 64;
  f32x4 acc[4][4] = {};
  for (int kt = 0; kt < K; kt += 64) {
    __syncthreads();
#pragma unroll
    for (int j = 0; j < 4; ++j) {
      int chunk = wave * 4 + j;          // 16 chunks of 1KB each per tile
      int e = chunk * 512 + lane * 8;    // element index in 128x64 tile
      int r = e >> 6, c = e & 63;
      gll16((u16*)As + chunk * 512, &A[(size_t)(bm + r) * K + kt + c]);
      gll16((u16*)Bs + chunk * 512, &Bt[(size_t)(bn + r) * K + kt + c]);
    }
    __syncthreads();
#pragma unroll
    for (int kk = 0; kk < 64; kk += 32) {
      bf16x8 af[4], bfr[4];
#pragma unroll
      for (int m = 0; m < 4; ++m)
        af[m] = *(const bf16x8*)&As[wm + m * 16 + lr][kk + g * 8];
#pragma unroll
      for (int n = 0; n < 4; ++n)
        bfr[n] = *(const bf16x8*)&Bs[wn + n * 16 + lr][kk + g * 8];
#pragma unroll
      for (int m = 0; m < 4; ++m)
#pragma unroll
        for (int n = 0; n < 4; ++n)
          acc[m][n] = __builtin_amdgcn_mfma_f32_16x16x32_bf16(af[m], bfr[n], acc[m][n], 0, 0, 0);
    }
  }
#pragma unroll
  for (int m = 0; m < 4; ++m) {
#pragma unroll
    for (int n = 0; n < 4; ++n) {
      const int col = bn + wn + n * 16 + lr;
      float bv = bias ? bias[col] : 0.f;
      if (col < qn) bv *= QSCALE;
      if (vTout != nullptr && col >= vn0) {
        const int hc = col - vn0;   // h*64 + d
#pragma unroll
        for (int r = 0; r < 4; ++r) {
          const int row = bm + wm + m * 16 + g * 4 + r;   // b*2048 + t
          const size_t idx = (((size_t)(row >> 11) * 16 + (hc >> 6)) * 64 + (hc & 63)) * 2048
                             + (row & 2047);
          vTout[idx] = f2bf(acc[m][n][r] + bv);
        }
      } else {
#pragma unroll
        for (int r = 0; r < 4; ++r) {
          const int row = bm + wm + m * 16 + g * 4 + r;   // C/D: col=lane&15, row=(lane>>4)*4+reg
          float v = acc[m][n][r] + bv;
          if (OUT_BF16) ((u16*)Cout)[(size_t)row * N + col] = f2bf(v);
          else          ((float*)Cout)[(size_t)row * N + col] = v;
        }
      }
    }
  }
}

// ---------------- flash attention: 32 q-rows/wave, swapped QK^T, in-reg softmax ----
// grid (S/128, B*H); block 256 = 4 waves; wave w owns q rows [q0+32w, q0+32w+32)
// split as two 16-row groups gq=0,1. qkv: [B*S][3072] bf16 (Q pre-scaled by QSCALE);
// vT: [bh][d][t]. Swapped QK: s{gq}[n] = mfma(kf, qf{gq}) ->
// s{gq}[n][r] = S[key=n*16+g*4+r][q = gq*16+lr]. K/V fragments are reused across
// both q-groups -> ~45% less LDS read traffic per FLOP vs 16 q-rows/wave.

DEV float rowmax(const f32x4* s) {
  f32x4 t01, t23;
#pragma unroll
  for (int i = 0; i < 4; ++i) {
    t01[i] = fmaxf(s[0][i], s[1][i]);
    t23[i] = fmaxf(s[2][i], s[3][i]);
  }
  return fmaxf(fmaxf(fmaxf(t01[0], t23[0]), fmaxf(t01[1], t23[1])),
               fmaxf(fmaxf(t01[2], t23[2]), fmaxf(t01[3], t23[3])));
}

DEV void rescale(f32x4* o, float& lsum, float& m, float pm, int g) {
  float a = fmaxf(pm, __shfl_xor(pm, 16));
  a = fmaxf(a, __shfl_xor(a, 32));
  float mn = fmaxf(m, a);
  float sc = __builtin_amdgcn_exp2f(m - mn);
  float x0 = __shfl(sc, g * 4 + 0), x1 = __shfl(sc, g * 4 + 1);
  float x2 = __shfl(sc, g * 4 + 2), x3 = __shfl(sc, g * 4 + 3);
#pragma unroll
  for (int nd = 0; nd < 4; ++nd) {
    o[nd][0] *= x0; o[nd][1] *= x1; o[nd][2] *= x2; o[nd][3] *= x3;
  }
  lsum *= sc;
  m = mn;
}

DEV float expwrite(const f32x4* s, float m, char* pbase, const int* pwo) {
  float su = 0.f;
#pragma unroll
  for (int n = 0; n < 4; ++n) {
    float p0 = __builtin_amdgcn_exp2f(s[n][0] - m);
    float p1 = __builtin_amdgcn_exp2f(s[n][1] - m);
    float p2 = __builtin_amdgcn_exp2f(s[n][2] - m);
    float p3 = __builtin_amdgcn_exp2f(s[n][3] - m);
    uint2 w;
    w.x = pk2(p0, p1);
    w.y = pk2(p2, p3);
    *(uint2*)(pbase + pwo[n]) = w;   // keys n*16+g*4+0..3
    su += (p0 + p1) + (p2 + p3);
  }
  return su;
}

#define ATTN_BODY(BUF, PRE)                                                       \
  {                                                                               \
    if (PRE) {                                                                    \
      gll16((u16*)Ks[(BUF) ^ 1] + c0 * 512, gk0); gk0 += 64 * 3072;               \
      gll16((u16*)Ks[(BUF) ^ 1] + c1 * 512, gk1); gk1 += 64 * 3072;               \
      gll16((u16*)Vs[(BUF) ^ 1] + c0 * 512, gv0); gv0 += 64;                      \
      gll16((u16*)Vs[(BUF) ^ 1] + c1 * 512, gv1); gv1 += 64;                      \
    }                                                                             \
    const char* kb = (const char*)Ks[(BUF)];                                      \
    const char* vb = (const char*)Vs[(BUF)];                                      \
    f32x4 s0[4] = {}, s1[4] = {};                                                 \
    _Pragma("unroll")                                                             \
    for (int kk = 0; kk < 2; ++kk)                                                \
      _Pragma("unroll")                                                           \
      for (int n = 0; n < 4; ++n) {                                               \
        bf16x8 kf = *(const bf16x8*)(kb + off[kk][n]);                            \
        s0[n] = __builtin_amdgcn_mfma_f32_16x16x32_bf16(kf, qf0[kk], s0[n], 0, 0, 0); \
        s1[n] = __builtin_amdgcn_mfma_f32_16x16x32_bf16(kf, qf1[kk], s1[n], 0, 0, 0); \
      }                                                                           \
    float pm0 = rowmax(s0), pm1 = rowmax(s1);                                     \
    if (!__all((pm0 <= m0 + 8.f) && (pm1 <= m1 + 8.f))) {                         \
      rescale(o0, lsum0, m0, pm0, g);                                             \
      rescale(o1, lsum1, m1, pm1, g);                                             \
    }                                                                             \
    lsum0 += expwrite(s0, m0, pb, pwo);                                           \
    lsum1 += expwrite(s1, m1, pb + 2048, pwo);                                    \
    _Pragma("unroll")                                                             \
    for (int kk = 0; kk < 2; ++kk) {                                              \
      bf16x8 pf0 = *(const bf16x8*)(pb + off[kk][0]);                             \
      bf16x8 pf1 = *(const bf16x8*)(pb + off[kk][1]);                             \
      _Pragma("unroll")                                                           \
      for (int nd = 0; nd < 4; ++nd) {                                            \
        bf16x8 vf = *(const bf16x8*)(vb + off[kk][nd]);                           \
        o0[nd] = __builtin_amdgcn_mfma_f32_16x16x32_bf16(pf0, vf, o0[nd], 0, 0, 0); \
        o1[nd] = __builtin_amdgcn_mfma_f32_16x16x32_bf16(pf1, vf, o1[nd], 0, 0, 0); \
      }                                                                           \
    }                                                                             \
    __syncthreads();                                                              \
  }

__global__ __launch_bounds__(256) void attn_kernel(const u16* __restrict__ qkv,
                                                   const u16* __restrict__ vT,
                                                   u16* __restrict__ out) {
  __shared__ __align__(16) u16 Ks[2][4096];   // K tile [key][d], swizzled
  __shared__ __align__(16) u16 Vs[2][4096];   // V^T tile [d][key], swizzled
  __shared__ __align__(16) u16 Ps[4][2048];   // per-wave P [32 qrows][64 keys], swizzled
  const int tid = threadIdx.x;
  const int wave = tid >> 6, lane = tid & 63;
  const int g = lane >> 4, lr = lane & 15;
  const int bh = blockIdx.y;
  const int b = bh >> 4, h = bh & 15;
  const int q0 = blockIdx.x * 128;
  const size_t base = (size_t)b * 2048 * 3072;
  const u16* kg = qkv + base + 1024 + h * 64;        // + t*3072 + d
  const u16* vg = vT + (size_t)bh * 64 * 2048;       // + d*2048 + t

  const int qrow = q0 + wave * 32 + lr;
  bf16x8 qf0[2], qf1[2];
#pragma unroll
  for (int kk = 0; kk < 2; ++kk) {
    qf0[kk] = *(const bf16x8*)&qkv[base + (size_t)qrow * 3072 + h * 64 + kk * 32 + g * 8];
    qf1[kk] = *(const bf16x8*)&qkv[base + (size_t)(qrow + 16) * 3072 + h * 64 + kk * 32 + g * 8];
  }

  // loop-invariant swizzled LDS byte offsets (shared by K-reads, V-reads, P-reads)
  const int sw = (lr & 7) << 4;
  int off[2][4];
#pragma unroll
  for (int kk = 0; kk < 2; ++kk)
#pragma unroll
    for (int n = 0; n < 4; ++n)
      off[kk][n] = (n * 16 + lr) * 128 + ((kk * 64 + g * 16) ^ sw);
  int pwo[4];
#pragma unroll
  for (int n = 0; n < 4; ++n)
    pwo[n] = lr * 128 + ((n * 32 + g * 8) ^ sw);
  char* const pb = (char*)Ps[wave];

  // per-lane incremental stage source pointers (r/cb decode done once)
  const int c0 = wave * 2, c1 = c0 + 1;
  const int a0 = c0 * 1024 + lane * 16, a1 = c1 * 1024 + lane * 16;
  const int r0 = a0 >> 7, r1 = a1 >> 7;
  const int cb0 = (a0 & 127) ^ ((r0 & 7) << 4), cb1 = (a1 & 127) ^ ((r1 & 7) << 4);
  const u16* gk0 = kg + (size_t)r0 * 3072 + (cb0 >> 1);
  const u16* gk1 = kg + (size_t)r1 * 3072 + (cb1 >> 1);
  const u16* gv0 = vg + (size_t)r0 * 2048 + (cb0 >> 1);
  const u16* gv1 = vg + (size_t)r1 * 2048 + (cb1 >> 1);

  f32x4 o0[4] = {}, o1[4] = {};
  float m0 = -1e30f, m1 = -1e30f, lsum0 = 0.f, lsum1 = 0.f;

  // prologue: stage tile 0 into buf 0
  gll16((u16*)Ks[0] + c0 * 512, gk0); gk0 += 64 * 3072;
  gll16((u16*)Ks[0] + c1 * 512, gk1); gk1 += 64 * 3072;
  gll16((u16*)Vs[0] + c0 * 512, gv0); gv0 += 64;
  gll16((u16*)Vs[0] + c1 * 512, gv1); gv1 += 64;
  __syncthreads();

  for (int it2 = 0; it2 < 16; ++it2) {
    ATTN_BODY(0, 1)
    ATTN_BODY(1, it2 < 15)
  }

  // final row-sum reduce + redistribute to o's rows (g*4+r)
  float lf0 = lsum0 + __shfl_xor(lsum0, 16); lf0 += __shfl_xor(lf0, 32);
  float lf1 = lsum1 + __shfl_xor(lsum1, 16); lf1 += __shfl_xor(lf1, 32);
  float l00 = __shfl(lf0, g * 4 + 0), l01 = __shfl(lf0, g * 4 + 1);
  float l02 = __shfl(lf0, g * 4 + 2), l03 = __shfl(lf0, g * 4 + 3);
  float l10 = __shfl(lf1, g * 4 + 0), l11 = __shfl(lf1, g * 4 + 1);
  float l12 = __shfl(lf1, g * 4 + 2), l13 = __shfl(lf1, g * 4 + 3);
  const size_t orow0 = (size_t)b * 2048 + q0 + wave * 32;
#pragma unroll
  for (int nd = 0; nd < 4; ++nd) {
    const int dcol = h * 64 + nd * 16 + lr;
    out[(orow0 + g * 4 + 0) * 1024 + dcol] = f2bf(o0[nd][0] / l00);
    out[(orow0 + g * 4 + 1) * 1024 + dcol] = f2bf(o0[nd][1] / l01);
    out[(orow0 + g * 4 + 2) * 1024 + dcol] = f2bf(o0[nd][2] / l02);
    out[(orow0 + g * 4 + 3) * 1024 + dcol] = f2bf(o0[nd][3] / l03);
    out[(orow0 + 16 + g * 4 + 0) * 1024 + dcol] = f2bf(o1[nd][0] / l10);
    out[(orow0 + 16 + g * 4 + 1) * 1024 + dcol] = f2bf(o1[nd][1] / l11);
    out[(orow0 + 16 + g * 4 + 2) * 1024 + dcol] = f2bf(o1[nd][2] / l12);
    out[(orow0 + 16 + g * 4 + 3) * 1024 + dcol] = f2bf(o1[nd][3] / l13);
  }
}

// ---------------- launcher ----------------
extern "C" void kernel_launch(void* const* d_in, const int* in_sizes, int n_in,
                              void* d_out, int out_size, void* d_ws, size_t ws_size,
                              hipStream_t stream) {
  (void)in_sizes; (void)n_in; (void)out_size;
  const float* x     = (const float*)d_in[0];  // [4,2048,1024]
  const float* w_in  = (const float*)d_in[1];  // [1024,3072]
  const float* b_in  = (const float*)d_in[2];  // [3072]
  const float* w_out = (const float*)d_in[3];  // [1024,1024]
  const float* b_out = (const float*)d_in[4];  // [1024]
  float* out = (float*)d_out;                  // [4,2048,1024] fp32

  char* ws = (char*)d_ws;
  u16* Xbf   = (u16*)ws; ws += (size_t)8192 * 1024 * 2;  // 16.8 MB
  u16* WinT  = (u16*)ws; ws += (size_t)3072 * 1024 * 2;  //  6.3 MB
  u16* WoutT = (u16*)ws; ws += (size_t)1024 * 1024 * 2;  //  2.1 MB
  u16* qkv   = (u16*)ws; ws += (size_t)8192 * 3072 * 2;  // 50.3 MB
  u16* attno = (u16*)ws; ws += (size_t)8192 * 1024 * 2;  // 16.8 MB  (base total ~92.3 MB)
  u16* vTsep = (u16*)ws;                                  // +16.8 MB if it fits

  const size_t fused_need = 92274688ull + 16777216ull;   // 109 MB
  const bool fused = (ws_size >= fused_need);
  u16* vT = fused ? vTsep : Xbf;   // fallback: alias Xbf (dead after gemm1)

  cvt_f32_to_bf16<<<2048, 256, 0, stream>>>(x, Xbf, 8192 * 1024 / 4);
  transpose_cvt<<<dim3(16, 48), 256, 0, stream>>>(w_in, WinT, 1024, 3072, 1024, QSCALE);
  transpose_cvt<<<dim3(16, 16), 256, 0, stream>>>(w_out, WoutT, 1024, 1024, 0, 1.0f);
  if (fused) {
    // V columns written directly in vT[bh][d][t] layout by the GEMM epilogue
    gemm_bf16<true ><<<dim3(64, 24), 256, 0, stream>>>(Xbf, WinT, b_in, qkv,
                                                       8192, 3072, 1024, 1024, vT, 2048);
  } else {
    gemm_bf16<true ><<<dim3(64, 24), 256, 0, stream>>>(Xbf, WinT, b_in, qkv,
                                                       8192, 3072, 1024, 1024, nullptr, 1 << 30);
    transpose_v<<<dim3(32, 64), 256, 0, stream>>>(qkv, vT);
  }
  attn_kernel<<<dim3(16, 64), 256, 0, stream>>>(qkv, vT, attno);
  gemm_bf16<false><<<dim3(64, 8), 256, 0, stream>>>(attno, WoutT, b_out, out,
                                                    8192, 1024, 1024, 0, nullptr, 1 << 30);
}

// Round 6
// 237.792 us; speedup vs baseline: 1.0716x; 1.0716x over previous
//
#include <hip/hip_runtime.h>
#include <hip/hip_bf16.h>

typedef unsigned short u16;
typedef __attribute__((ext_vector_type(8))) short bf16x8;
typedef __attribute__((ext_vector_type(4))) float f32x4;

#define QSCALE 0.180336880f   // 0.125 * log2(e): softmax computed in exp2 domain

#define DEV static __device__ __forceinline__

DEV u16 f2bf(float f) {
  union { float f; unsigned u; } v; v.f = f;
  unsigned r = v.u + 0x7fffu + ((v.u >> 16) & 1u);  // round-to-nearest-even
  return (u16)(r >> 16);
}

DEV unsigned pk2(float a, float b) {   // two f32 -> packed bf16x2 (RNE)
  union { __hip_bfloat162 h; unsigned u; } c;
  c.h = __float22bfloat162_rn(make_float2(a, b));
  return c.u;
}

DEV void gll16(void* lds, const void* g) {
  __builtin_amdgcn_global_load_lds(
      (const __attribute__((address_space(1))) unsigned int*)g,
      (__attribute__((address_space(3))) unsigned int*)lds, 16, 0, 0);
}

// ---------------- pack: fp32 -> bf16 ----------------
__global__ __launch_bounds__(256) void cvt_f32_to_bf16(const float* __restrict__ in,
                                                       u16* __restrict__ out, int n4) {
  int i = blockIdx.x * blockDim.x + threadIdx.x;
  int stride = gridDim.x * blockDim.x;
  for (; i < n4; i += stride) {
    float4 f = ((const float4*)in)[i];
    ushort4 u;
    u.x = f2bf(f.x); u.y = f2bf(f.y); u.z = f2bf(f.z); u.w = f2bf(f.w);
    ((ushort4*)out)[i] = u;
  }
}

// ---------------- pack: W[K][N] fp32 -> Wt[N][K] bf16, cols < sn scaled ----------------
__global__ __launch_bounds__(256) void transpose_cvt(const float* __restrict__ W,
                                                     u16* __restrict__ Wt,
                                                     int K, int N, int sn, float sval) {
  __shared__ u16 t[64][65];
  const int k0 = blockIdx.x * 64, n0 = blockIdx.y * 64;
  const int tid = threadIdx.x;
  const int rr = tid >> 4;        // 0..15
  const int cc = (tid & 15) * 4;  // 0..60
  const float scl = (n0 < sn) ? sval : 1.0f;   // n0 is 64-aligned, sn is 1024
#pragma unroll
  for (int i = 0; i < 4; ++i) {
    const int row = rr * 4 + i;
    float4 f = *(const float4*)&W[(size_t)(k0 + row) * N + n0 + cc];
    t[row][cc + 0] = f2bf(f.x * scl);
    t[row][cc + 1] = f2bf(f.y * scl);
    t[row][cc + 2] = f2bf(f.z * scl);
    t[row][cc + 3] = f2bf(f.w * scl);
  }
  __syncthreads();
#pragma unroll
  for (int i = 0; i < 4; ++i) {
    const int n = rr * 4 + i;
    ushort4 u;
    u.x = t[cc + 0][n]; u.y = t[cc + 1][n]; u.z = t[cc + 2][n]; u.w = t[cc + 3][n];
    *(ushort4*)&Wt[(size_t)(n0 + n) * K + k0 + cc] = u;
  }
}

// ---------------- transpose V part of qkv: -> vT[bh][d][t] (fallback path) --------
__global__ __launch_bounds__(256) void transpose_v(const u16* __restrict__ qkv,
                                                   u16* __restrict__ vT) {
  __shared__ u16 t[64][72];
  const int bh = blockIdx.y;          // b*16+h
  const int b = bh >> 4, h = bh & 15;
  const int t0 = blockIdx.x * 64;
  const int tid = threadIdx.x;
  const int row = tid >> 2;           // token within tile, 0..63
  const int cg = (tid & 3) * 16;      // d group
  const size_t src = (size_t)b * 2048 * 3072 + (size_t)(t0 + row) * 3072 + 2048 + h * 64 + cg;
  bf16x8 v0 = *(const bf16x8*)&qkv[src];
  bf16x8 v1 = *(const bf16x8*)&qkv[src + 8];
#pragma unroll
  for (int i = 0; i < 8; ++i) { t[row][cg + i] = (u16)v0[i]; t[row][cg + 8 + i] = (u16)v1[i]; }
  __syncthreads();
  const int d = tid >> 2;             // 0..63
  const int tg = (tid & 3) * 16;
  bf16x8 o0, o1;
#pragma unroll
  for (int i = 0; i < 8; ++i) { o0[i] = (short)t[tg + i][d]; o1[i] = (short)t[tg + 8 + i][d]; }
  u16* dst = &vT[((size_t)bh * 64 + d) * 2048 + t0 + tg];
  *(bf16x8*)dst = o0;
  *(bf16x8*)(dst + 8) = o1;
}

// ---------------- bf16 GEMM: C[M][N] = A[M][K] * Bt[N][K]^T + bias ----------------
// 128x128 tile, BK=64, 256 threads (4 waves, 2x2), each wave 64x64 = 4x4 frags.
// Bias for cols < qn scaled by QSCALE. If vTout != null, cols >= vn0 are written
// transposed to vT[bh][d][t] layout instead of Cout (fused V-transpose).
template<bool OUT_BF16>
__global__ __launch_bounds__(256) void gemm_bf16(const u16* __restrict__ A,
                                                 const u16* __restrict__ Bt,
                                                 const float* __restrict__ bias,
                                                 void* __restrict__ Cout,
                                                 int M, int N, int K, int qn,
                                                 u16* __restrict__ vTout, int vn0) {
  __shared__ __align__(16) u16 As[128][64];
  __shared__ __align__(16) u16 Bs[128][64];
  const int tid = threadIdx.x;
  const int wave = tid >> 6, lane = tid & 63;
  const int g = lane >> 4, lr = lane & 15;
  const int bm = blockIdx.x * 128, bn = blockIdx.y * 128;
  const int wm = (wave >> 1) * 64, wn = (wave & 1) * 64;
  f32x4 acc[4][4] = {};
  for (int kt = 0; kt < K; kt += 64) {
    __syncthreads();
#pragma unroll
    for (int j = 0; j < 4; ++j) {
      int chunk = wave * 4 + j;          // 16 chunks of 1KB each per tile
      int e = chunk * 512 + lane * 8;    // element index in 128x64 tile
      int r = e >> 6, c = e & 63;
      gll16((u16*)As + chunk * 512, &A[(size_t)(bm + r) * K + kt + c]);
      gll16((u16*)Bs + chunk * 512, &Bt[(size_t)(bn + r) * K + kt + c]);
    }
    __syncthreads();
#pragma unroll
    for (int kk = 0; kk < 64; kk += 32) {
      bf16x8 af[4], bfr[4];
#pragma unroll
      for (int m = 0; m < 4; ++m)
        af[m] = *(const bf16x8*)&As[wm + m * 16 + lr][kk + g * 8];
#pragma unroll
      for (int n = 0; n < 4; ++n)
        bfr[n] = *(const bf16x8*)&Bs[wn + n * 16 + lr][kk + g * 8];
#pragma unroll
      for (int m = 0; m < 4; ++m)
#pragma unroll
        for (int n = 0; n < 4; ++n)
          acc[m][n] = __builtin_amdgcn_mfma_f32_16x16x32_bf16(af[m], bfr[n], acc[m][n], 0, 0, 0);
    }
  }
#pragma unroll
  for (int m = 0; m < 4; ++m) {
#pragma unroll
    for (int n = 0; n < 4; ++n) {
      const int col = bn + wn + n * 16 + lr;
      float bv = bias ? bias[col] : 0.f;
      if (col < qn) bv *= QSCALE;
      if (vTout != nullptr && col >= vn0) {
        const int hc = col - vn0;   // h*64 + d
#pragma unroll
        for (int r = 0; r < 4; ++r) {
          const int row = bm + wm + m * 16 + g * 4 + r;   // b*2048 + t
          const size_t idx = (((size_t)(row >> 11) * 16 + (hc >> 6)) * 64 + (hc & 63)) * 2048
                             + (row & 2047);
          vTout[idx] = f2bf(acc[m][n][r] + bv);
        }
      } else {
#pragma unroll
        for (int r = 0; r < 4; ++r) {
          const int row = bm + wm + m * 16 + g * 4 + r;   // C/D: col=lane&15, row=(lane>>4)*4+reg
          float v = acc[m][n][r] + bv;
          if (OUT_BF16) ((u16*)Cout)[(size_t)row * N + col] = f2bf(v);
          else          ((float*)Cout)[(size_t)row * N + col] = v;
        }
      }
    }
  }
}

// ---------------- flash attention: 32 q-rows/wave, KVBLK=32, 24KB LDS ----------------
// grid (S/128, B*H); block 256 = 4 waves; wave w owns q rows [q0+32w, q0+32w+32)
// as two 16-row groups. KV tile = 32 keys -> LDS 24KB -> all 4 blocks/CU resident
// (grid = 4 blocks/CU exactly, zero tail). K tile [32][64] (128B rows, swz (lr&7)<<4);
// V^T tile [64][32] and P [32 q][32 k] (64B rows, swz ((row^(row>>2))&3)<<4 so the
// 4-slot rows still spread across all banks).

DEV float rowmax2(const f32x4* s) {
  f32x4 t;
#pragma unroll
  for (int i = 0; i < 4; ++i) t[i] = fmaxf(s[0][i], s[1][i]);
  return fmaxf(fmaxf(t[0], t[1]), fmaxf(t[2], t[3]));
}

DEV void rescale(f32x4* o, float& lsum, float& m, float pm, int g) {
  float a = fmaxf(pm, __shfl_xor(pm, 16));
  a = fmaxf(a, __shfl_xor(a, 32));
  float mn = fmaxf(m, a);
  float sc = __builtin_amdgcn_exp2f(m - mn);
  float x0 = __shfl(sc, g * 4 + 0), x1 = __shfl(sc, g * 4 + 1);
  float x2 = __shfl(sc, g * 4 + 2), x3 = __shfl(sc, g * 4 + 3);
#pragma unroll
  for (int nd = 0; nd < 4; ++nd) {
    o[nd][0] *= x0; o[nd][1] *= x1; o[nd][2] *= x2; o[nd][3] *= x3;
  }
  lsum *= sc;
  m = mn;
}

DEV float expwrite2(const f32x4* s, float m, char* pbase, const int* pwo) {
  float su = 0.f;
#pragma unroll
  for (int n = 0; n < 2; ++n) {
    float p0 = __builtin_amdgcn_exp2f(s[n][0] - m);
    float p1 = __builtin_amdgcn_exp2f(s[n][1] - m);
    float p2 = __builtin_amdgcn_exp2f(s[n][2] - m);
    float p3 = __builtin_amdgcn_exp2f(s[n][3] - m);
    uint2 w;
    w.x = pk2(p0, p1);
    w.y = pk2(p2, p3);
    *(uint2*)(pbase + pwo[n]) = w;   // keys n*16+g*4+0..3
    su += (p0 + p1) + (p2 + p3);
  }
  return su;
}

#define ATTN_BODY(BUF, PRE)                                                       \
  {                                                                               \
    if (PRE) {                                                                    \
      gll16((u16*)Ks[(BUF) ^ 1] + wave * 512, gk); gk += 32 * 3072;               \
      gll16((u16*)Vs[(BUF) ^ 1] + wave * 512, gv); gv += 32;                      \
    }                                                                             \
    const char* kb = (const char*)Ks[(BUF)];                                      \
    const char* vb = (const char*)Vs[(BUF)];                                      \
    f32x4 s0[2] = {}, s1[2] = {};                                                 \
    _Pragma("unroll")                                                             \
    for (int kk = 0; kk < 2; ++kk)                                                \
      _Pragma("unroll")                                                           \
      for (int n = 0; n < 2; ++n) {                                               \
        bf16x8 kf = *(const bf16x8*)(kb + koff[kk][n]);                           \
        s0[n] = __builtin_amdgcn_mfma_f32_16x16x32_bf16(kf, qf0[kk], s0[n], 0, 0, 0); \
        s1[n] = __builtin_amdgcn_mfma_f32_16x16x32_bf16(kf, qf1[kk], s1[n], 0, 0, 0); \
      }                                                                           \
    float pm0 = rowmax2(s0), pm1 = rowmax2(s1);                                   \
    if (!__all((pm0 <= m0 + 8.f) && (pm1 <= m1 + 8.f))) {                         \
      rescale(o0, lsum0, m0, pm0, g);                                             \
      rescale(o1, lsum1, m1, pm1, g);                                             \
    }                                                                             \
    lsum0 += expwrite2(s0, m0, pb, pwo);                                          \
    lsum1 += expwrite2(s1, m1, pb + 1024, pwo);                                   \
    bf16x8 pf0 = *(const bf16x8*)(pb + poff);                                     \
    bf16x8 pf1 = *(const bf16x8*)(pb + 1024 + poff);                              \
    _Pragma("unroll")                                                             \
    for (int nd = 0; nd < 4; ++nd) {                                              \
      bf16x8 vf = *(const bf16x8*)(vb + voff[nd]);                                \
      o0[nd] = __builtin_amdgcn_mfma_f32_16x16x32_bf16(pf0, vf, o0[nd], 0, 0, 0); \
      o1[nd] = __builtin_amdgcn_mfma_f32_16x16x32_bf16(pf1, vf, o1[nd], 0, 0, 0); \
    }                                                                             \
    __syncthreads();                                                              \
  }

__global__ __launch_bounds__(256, 4) void attn_kernel(const u16* __restrict__ qkv,
                                                      const u16* __restrict__ vT,
                                                      u16* __restrict__ out) {
  __shared__ __align__(16) u16 Ks[2][2048];   // K tile [32 key][64 d], swizzled
  __shared__ __align__(16) u16 Vs[2][2048];   // V^T tile [64 d][32 key], swizzled
  __shared__ __align__(16) u16 Ps[4][1024];   // per-wave P [32 q][32 key], swizzled
  const int tid = threadIdx.x;
  const int wave = tid >> 6, lane = tid & 63;
  const int g = lane >> 4, lr = lane & 15;
  const int bh = blockIdx.y;
  const int b = bh >> 4, h = bh & 15;
  const int q0 = blockIdx.x * 128;
  const size_t base = (size_t)b * 2048 * 3072;
  const u16* kg = qkv + base + 1024 + h * 64;        // + t*3072 + d
  const u16* vg = vT + (size_t)bh * 64 * 2048;       // + d*2048 + t

  const int qrow = q0 + wave * 32 + lr;
  bf16x8 qf0[2], qf1[2];
#pragma unroll
  for (int kk = 0; kk < 2; ++kk) {
    qf0[kk] = *(const bf16x8*)&qkv[base + (size_t)qrow * 3072 + h * 64 + kk * 32 + g * 8];
    qf1[kk] = *(const bf16x8*)&qkv[base + (size_t)(qrow + 16) * 3072 + h * 64 + kk * 32 + g * 8];
  }

  // loop-invariant swizzled LDS byte offsets
  const int sw7 = (lr & 7) << 4;                     // 128B-row tiles (K)
  const int swv = ((lr ^ (lr >> 2)) & 3) << 4;       // 64B-row tiles (V^T, P)
  int koff[2][2];
#pragma unroll
  for (int kk = 0; kk < 2; ++kk)
#pragma unroll
    for (int n = 0; n < 2; ++n)
      koff[kk][n] = (n * 16 + lr) * 128 + ((kk * 64 + g * 16) ^ sw7);
  int voff[4];
#pragma unroll
  for (int nd = 0; nd < 4; ++nd)
    voff[nd] = (nd * 16 + lr) * 64 + ((g * 16) ^ swv);
  const int poff = lr * 64 + ((g * 16) ^ swv);
  int pwo[2];
#pragma unroll
  for (int n = 0; n < 2; ++n)
    pwo[n] = lr * 64 + ((n * 32 + g * 8) ^ swv);
  char* const pb = (char*)Ps[wave];

  // per-lane incremental stage source pointers (inverse-swizzled, decoded once)
  const int a = wave * 1024 + lane * 16;             // linear LDS byte this lane DMAs
  const int kr = a >> 7;                             // K-tile row (128B rows)
  const int kcb = (a & 127) ^ ((kr & 7) << 4);
  const int vr = a >> 6;                             // V-tile row (64B rows)
  const int vcb = (a & 63) ^ (((vr ^ (vr >> 2)) & 3) << 4);
  const u16* gk = kg + (size_t)kr * 3072 + (kcb >> 1);
  const u16* gv = vg + (size_t)vr * 2048 + (vcb >> 1);

  f32x4 o0[4] = {}, o1[4] = {};
  float m0 = -1e30f, m1 = -1e30f, lsum0 = 0.f, lsum1 = 0.f;

  // prologue: stage tile 0 into buf 0
  gll16((u16*)Ks[0] + wave * 512, gk); gk += 32 * 3072;
  gll16((u16*)Vs[0] + wave * 512, gv); gv += 32;
  __syncthreads();

  for (int it2 = 0; it2 < 32; ++it2) {
    ATTN_BODY(0, 1)
    ATTN_BODY(1, it2 < 31)
  }

  // final row-sum reduce + redistribute to o's rows (g*4+r)
  float lf0 = lsum0 + __shfl_xor(lsum0, 16); lf0 += __shfl_xor(lf0, 32);
  float lf1 = lsum1 + __shfl_xor(lsum1, 16); lf1 += __shfl_xor(lf1, 32);
  float l00 = __shfl(lf0, g * 4 + 0), l01 = __shfl(lf0, g * 4 + 1);
  float l02 = __shfl(lf0, g * 4 + 2), l03 = __shfl(lf0, g * 4 + 3);
  float l10 = __shfl(lf1, g * 4 + 0), l11 = __shfl(lf1, g * 4 + 1);
  float l12 = __shfl(lf1, g * 4 + 2), l13 = __shfl(lf1, g * 4 + 3);
  const size_t orow0 = (size_t)b * 2048 + q0 + wave * 32;
#pragma unroll
  for (int nd = 0; nd < 4; ++nd) {
    const int dcol = h * 64 + nd * 16 + lr;
    out[(orow0 + g * 4 + 0) * 1024 + dcol] = f2bf(o0[nd][0] / l00);
    out[(orow0 + g * 4 + 1) * 1024 + dcol] = f2bf(o0[nd][1] / l01);
    out[(orow0 + g * 4 + 2) * 1024 + dcol] = f2bf(o0[nd][2] / l02);
    out[(orow0 + g * 4 + 3) * 1024 + dcol] = f2bf(o0[nd][3] / l03);
    out[(orow0 + 16 + g * 4 + 0) * 1024 + dcol] = f2bf(o1[nd][0] / l10);
    out[(orow0 + 16 + g * 4 + 1) * 1024 + dcol] = f2bf(o1[nd][1] / l11);
    out[(orow0 + 16 + g * 4 + 2) * 1024 + dcol] = f2bf(o1[nd][2] / l12);
    out[(orow0 + 16 + g * 4 + 3) * 1024 + dcol] = f2bf(o1[nd][3] / l13);
  }
}

// ---------------- launcher ----------------
extern "C" void kernel_launch(void* const* d_in, const int* in_sizes, int n_in,
                              void* d_out, int out_size, void* d_ws, size_t ws_size,
                              hipStream_t stream) {
  (void)in_sizes; (void)n_in; (void)out_size;
  const float* x     = (const float*)d_in[0];  // [4,2048,1024]
  const float* w_in  = (const float*)d_in[1];  // [1024,3072]
  const float* b_in  = (const float*)d_in[2];  // [3072]
  const float* w_out = (const float*)d_in[3];  // [1024,1024]
  const float* b_out = (const float*)d_in[4];  // [1024]
  float* out = (float*)d_out;                  // [4,2048,1024] fp32

  char* ws = (char*)d_ws;
  u16* Xbf   = (u16*)ws; ws += (size_t)8192 * 1024 * 2;  // 16.8 MB
  u16* WinT  = (u16*)ws; ws += (size_t)3072 * 1024 * 2;  //  6.3 MB
  u16* WoutT = (u16*)ws; ws += (size_t)1024 * 1024 * 2;  //  2.1 MB
  u16* qkv   = (u16*)ws; ws += (size_t)8192 * 3072 * 2;  // 50.3 MB
  u16* attno = (u16*)ws; ws += (size_t)8192 * 1024 * 2;  // 16.8 MB  (base total ~92.3 MB)
  u16* vTsep = (u16*)ws;                                  // +16.8 MB if it fits

  const size_t fused_need = 92274688ull + 16777216ull;   // 109 MB
  const bool fused = (ws_size >= fused_need);
  u16* vT = fused ? vTsep : Xbf;   // fallback: alias Xbf (dead after gemm1)

  cvt_f32_to_bf16<<<2048, 256, 0, stream>>>(x, Xbf, 8192 * 1024 / 4);
  transpose_cvt<<<dim3(16, 48), 256, 0, stream>>>(w_in, WinT, 1024, 3072, 1024, QSCALE);
  transpose_cvt<<<dim3(16, 16), 256, 0, stream>>>(w_out, WoutT, 1024, 1024, 0, 1.0f);
  if (fused) {
    // V columns written directly in vT[bh][d][t] layout by the GEMM epilogue
    gemm_bf16<true ><<<dim3(64, 24), 256, 0, stream>>>(Xbf, WinT, b_in, qkv,
                                                       8192, 3072, 1024, 1024, vT, 2048);
  } else {
    gemm_bf16<true ><<<dim3(64, 24), 256, 0, stream>>>(Xbf, WinT, b_in, qkv,
                                                       8192, 3072, 1024, 1024, nullptr, 1 << 30);
    transpose_v<<<dim3(32, 64), 256, 0, stream>>>(qkv, vT);
  }
  attn_kernel<<<dim3(16, 64), 256, 0, stream>>>(qkv, vT, attno);
  gemm_bf16<false><<<dim3(64, 8), 256, 0, stream>>>(attno, WoutT, b_out, out,
                                                    8192, 1024, 1024, 0, nullptr, 1 << 30);
}